// Round 12
// baseline (81.145 us; speedup 1.0000x reference)
//
#include <hip/hip_runtime.h>
#include <math.h>

// SpectralPooling: out = Re(ifft3_32(pad32(crop24(Re(fft3_48(x))))))  per (b,c) volume.
// bc = 256 volumes of 48^3 fp32 -> 256 x 32^3 fp32.
//
// r21 = r20 (best, 79.2us) + K1 -> 6 SLABS PER WAVE, SOFTWARE-PIPELINED.
// Evidence: r16-r20 all run K1 as 1 slab/wave cold-start and all land ~50-55us
// regardless of schedule -> the invariant is the granularity. 6 slabs/wave:
//  (a) slab g+1's 12 X loads issue right after GEMM1 consumes slab g's regs ->
//      loads outstanding across GEMM2+dumps+epilogue (formerly dead 2/3 of chain);
//  (b) T1+T2 (24KB/wave of table reads) amortized 6x;
//  (c) grid 8x256 = 2048 = exactly one residency round at launch_bounds(64,2)
//      (8 one-wave blocks/CU, VGPR cap 256 fits peak live ~190).
// Pads re-zeroed PER SLAB (D2 overlay clobbers U pad bytes; per-wave DS order:
// epilogue D2-reads -> pad zero -> next U dump. Race-free). MFMA per-accumulator
// order verbatim r20 -> bitwise-identical output (absmax must stay 0.00390625).
//  K1 (per bc, 6 slabs/wave, zero barriers): D1 = T1*X ; D2 = D1*T2t ; -> V
//  K2 (per k3, 2x bc-pair): [Wr;Wi](64x48) = M_comb(64x96) * [Vr;Vi](96x48) -> W
//  K3 (per m1, 2x bc): [Zr;Zi] = MB2*[Wr;Wi] ; out = Z*TB3
// Split-f16 everywhere: P = Ahi*Bhi + Ahi*Blo + Alo*Bhi (~22 mantissa bits).
//
// d_ws: float2 V[256][24][48][24] (56,623,104 B) then
//       float2 W[256][32][24][24] (37,748,736 B) at byte offset 56,623,104.

#define TWO_PI_48 0.13089969389957470f
#define TWO_PI_32 0.19634954084936207f
#define NORM_F    1.6611664e-05f         // 1/(48^1.5 * 32^1.5)

typedef _Float16 half8  __attribute__((ext_vector_type(8)));
typedef _Float16 half4v __attribute__((ext_vector_type(4)));
typedef float    f32x4  __attribute__((ext_vector_type(4)));

// Frag-layout tables: [hi/lo][tile][kstep][lane][j]
// A-frag element = A[tile*16 + (l&15)][ks*32 + (l>>4)*8 + j]
// B-frag element = B[ks*32 + (l>>4)*8 + j][tile*16 + (l&15)]
__device__ _Float16 T1frag[2][3][2][64][8];
__device__ _Float16 T2frag[2][3][2][64][8];
__device__ __align__(16) _Float16 TK2frag[2][4][3][64][8];  // M_comb 64x96
__device__ __align__(16) _Float16 MB2frag[2][4][2][64][8];  // 64x48 (pad 64)
__device__ __align__(16) _Float16 TB3frag[2][2][2][64][8];  // 48(pad64)x32

__device__ int g_twdone = 0;   // lazy-init flag (module-lifetime, set post-init)

__global__ void k_init_tw() {
  if (g_twdone) return;                             // tables already built (pure consts)
  const int idx = blockIdx.x * 256 + threadIdx.x;   // 0..15359
  if (idx < 3072) {                                 // K1 tables (verified r5)
    const int j  = idx & 7;
    const int l  = (idx >> 3) & 63;
    const int ks = (idx >> 9) & 1;
    const int t  = idx >> 10;
    const int k  = ks * 32 + (l >> 4) * 8 + j;
    {
      const int m = t * 16 + (l & 15);
      float v = 0.f;
      if (k < 48) {
        const float a = (float)(((m % 24) * k) % 48) * TWO_PI_48;
        v = (m < 24) ? cosf(a) : -sinf(a);
      }
      const _Float16 h = (_Float16)v;
      T1frag[0][t][ks][l][j] = h;
      T1frag[1][t][ks][l][j] = (_Float16)(v - (float)h);
    }
    {
      const int c = t * 16 + (l & 15);
      float v = 0.f;
      if (k < 48) {
        const float a = (float)(((c % 24) * k) % 48) * TWO_PI_48;
        v = (c < 24) ? cosf(a) : sinf(a);
      }
      const _Float16 h = (_Float16)v;
      T2frag[0][t][ks][l][j] = h;
      T2frag[1][t][ks][l][j] = (_Float16)(v - (float)h);
    }
  } else if (idx < 3072 + 6144) {                   // K2: M_comb (A3+B1 fused)
    const int local = idx - 3072;
    const int j = local & 7, l = (local >> 3) & 63;
    const int rest = local >> 9;                    // 0..11
    const int ks = rest % 3, mt = rest / 3;
    const int m   = mt * 16 + (l & 15);             // 0..63
    const int kap = ks * 32 + (l >> 4) * 8 + j;     // 0..95
    const int n1  = kap % 48;
    const bool isVi = kap >= 48;
    const int m1  = m & 31;
    const bool isWi = m >= 32;
    float acc = 0.f;
    for (int k1 = 0; k1 < 24; ++k1) {
      float s32v, c32v, s48v, c48v;
      sincosf((float)((k1 * m1) % 32) * TWO_PI_32, &s32v, &c32v);
      sincosf((float)((k1 * n1) % 48) * TWO_PI_48, &s48v, &c48v);
      acc = fmaf(isWi ? s32v : c32v, isVi ? s48v : c48v, acc);
    }
    const _Float16 h = (_Float16)acc;
    TK2frag[0][mt][ks][l][j] = h;
    TK2frag[1][mt][ks][l][j] = (_Float16)(acc - (float)h);
  } else if (idx < 3072 + 6144 + 4096) {            // K3: MB2 (B2 A-matrix)
    const int local = idx - (3072 + 6144);
    const int j = local & 7, l = (local >> 3) & 63;
    const int rest = local >> 9;                    // 0..7
    const int ks = rest & 1, mt = rest >> 1;
    const int m   = mt * 16 + (l & 15);             // 0..63
    const int kap = ks * 32 + (l >> 4) * 8 + j;     // 0..63
    float v = 0.f;
    if (kap < 48) {
      const int k2 = kap % 24;
      const int m2 = m & 31;
      float s, c;
      sincosf((float)((k2 * m2) % 32) * TWO_PI_32, &s, &c);
      if (m < 32) v = (kap < 24) ? c : -s;   // Zr = sum Wr*c - Wi*s
      else        v = (kap < 24) ? s :  c;   // Zi = sum Wr*s + Wi*c
    }
    const _Float16 h = (_Float16)v;
    MB2frag[0][mt][ks][l][j] = h;
    MB2frag[1][mt][ks][l][j] = (_Float16)(v - (float)h);
  } else if (idx < 15360) {                         // K3: TB3 (B3 B-matrix)
    const int local = idx - (3072 + 6144 + 4096);
    const int j = local & 7, l = (local >> 3) & 63;
    const int rest = local >> 9;                    // 0..3
    const int ks = rest & 1, nt = rest >> 1;
    const int m3  = nt * 16 + (l & 15);             // col 0..31
    const int kap = ks * 32 + (l >> 4) * 8 + j;     // 0..63
    float v = 0.f;
    if (kap < 48) {
      const int k3 = kap % 24;
      float s, c;
      sincosf((float)((k3 * m3) % 32) * TWO_PI_32, &s, &c);
      v = (kap < 24) ? c : -s;               // out = sum Zr*c - Zi*s
    }
    const _Float16 h = (_Float16)v;
    TB3frag[0][nt][ks][l][j] = h;
    TB3frag[1][nt][ks][l][j] = (_Float16)(v - (float)h);
  }
}

__device__ inline void split8(const float* qf, half8& h, half8& lo) {
#pragma unroll
  for (int j = 0; j < 8; ++j) {
    const _Float16 hh = (_Float16)qf[j];
    h[j]  = hh;
    lo[j] = (_Float16)(qf[j] - (float)hh);
  }
}

// issue one slab's 12 X fragment loads (8 real float4 + 4 zero for k>=48)
__device__ inline void load_xf(const float* xs, int c16, int kb, float4 f[3][2][2]) {
  const int k1i = 32 + kb;
#pragma unroll
  for (int nt = 0; nt < 3; ++nt) {
    const int c = nt * 16 + c16;
    const float4* p0 = (const float4*)(xs + c * 48 + kb);
    f[nt][0][0] = p0[0]; f[nt][0][1] = p0[1];
    if (k1i < 48) {
      const float4* p1 = (const float4*)(xs + c * 48 + k1i);
      f[nt][1][0] = p1[0]; f[nt][1][1] = p1[1];
    } else {
      f[nt][1][0] = make_float4(0.f, 0.f, 0.f, 0.f);
      f[nt][1][1] = make_float4(0.f, 0.f, 0.f, 0.f);
    }
  }
}

// ---------------- K1: 6-slab pipelined wave, 64 thr, grid 8 x 256, ZERO barriers ----------------
// LDS arena (13824 B): Uh[48][72] f16 + Ul[48][72] f16; D2 f32 [48][68] OVERLAYS the
// arena after each GEMM2 (U dead; DS pipe in-order per wave).
// Per-slab DS order audit: U dump(g) -> U reads(g) -> D2 dump(g) [clobbers U data+pads]
// -> D2 reads(g, epilogue) -> pad re-zero(g) -> U dump(g+1). All same-wave, in-order.
// launch_bounds(64,2): VGPR cap 256 fits peak live ~190 (t1 48 + t2 48 + xf_next 48
// + a2 36 + misc); 8 blocks/CU x 256 CU = 2048 = grid -> exactly one round, no tail.
__global__ __launch_bounds__(64, 2) void k1_waveslab(const float* __restrict__ x,
                                                     float2* __restrict__ V) {
  const int bx   = blockIdx.x;   // 0..7 -> n1 = bx*6 + it
  const int bc   = blockIdx.y;   // 0..255
  const int lane = threadIdx.x;  // 0..63

  __shared__ __align__(16) unsigned char arena[13824];
  _Float16* Uh = (_Float16*)arena;
  _Float16* Ul = (_Float16*)(arena + 6912);
  float*    D2 = (float*)arena;               // overlay, used after each GEMM2

  const int c16  = lane & 15;
  const int kgrp = lane >> 4;    // 0..3
  const int kb   = kgrp * 8;

  const float* xc = x + (size_t)(bc * 48) * 2304;

  // prologue: issue slab-0 X loads FIRST (deepest latency), then twiddles, then pads.
  float4 xfA[3][2][2], xfB[3][2][2];
  load_xf(xc + (size_t)(bx * 6) * 2304, c16, kb, xfA);

  // twiddle fragments hoisted ONCE per wave (amortized over 6 slabs)
  half8 t1h[3][2], t1l[3][2], t2h[3][2], t2l[3][2];
#pragma unroll
  for (int mt = 0; mt < 3; ++mt)
#pragma unroll
    for (int ks = 0; ks < 2; ++ks) {
      t1h[mt][ks] = *(const half8*)&T1frag[0][mt][ks][lane][0];
      t1l[mt][ks] = *(const half8*)&T1frag[1][mt][ks][lane][0];
      t2h[mt][ks] = *(const half8*)&T2frag[0][mt][ks][lane][0];
      t2l[mt][ks] = *(const half8*)&T2frag[1][mt][ks][lane][0];
    }

  // zero U pad cols 48..63 (slab 0; re-zeroed per slab after D2 overlay clobbers)
#pragma unroll
  for (int p = 0; p < 3; ++p) {
    const int i = lane + 64 * p;            // 0..191
    const int which = i / 48, r = i % 48;
    _Float16* base = (which & 2) ? Ul : Uh;
    *(half8*)&base[r * 72 + 48 + (which & 1) * 8] = (half8){};
  }

#pragma unroll
  for (int it = 0; it < 6; ++it) {
    const int n1 = bx * 6 + it;
    float4 (&cur)[3][2][2] = (it & 1) ? xfB : xfA;
    float4 (&nxt)[3][2][2] = (it & 1) ? xfA : xfB;

    // ---- GEMM1: D1 = T1 * X, per col-tile nt; U dump after each nt ----
#pragma unroll
    for (int nt = 0; nt < 3; ++nt) {
      f32x4 acc0 = {}, acc1 = {}, acc2 = {};
#pragma unroll
      for (int ks = 0; ks < 2; ++ks) {
        const float4 qa = cur[nt][ks][0];
        const float4 qb = cur[nt][ks][1];
        const float qf[8] = {qa.x, qa.y, qa.z, qa.w, qb.x, qb.y, qb.z, qb.w};
        half8 bh, bl;
        split8(qf, bh, bl);
#pragma unroll
        for (int mt = 0; mt < 3; ++mt) {
          f32x4& acc = (mt == 0) ? acc0 : (mt == 1) ? acc1 : acc2;
          acc = __builtin_amdgcn_mfma_f32_16x16x32_f16(t1h[mt][ks], bh, acc, 0, 0, 0);
          acc = __builtin_amdgcn_mfma_f32_16x16x32_f16(t1h[mt][ks], bl, acc, 0, 0, 0);
          acc = __builtin_amdgcn_mfma_f32_16x16x32_f16(t1l[mt][ks], bh, acc, 0, 0, 0);
        }
      }
      // U dump for this nt (cols nt*16+c16)
      {
        const int cc = nt * 16 + c16;
#pragma unroll
        for (int mt = 0; mt < 3; ++mt) {
          const int r0 = mt * 16 + kgrp * 4;
          const f32x4 acc = (mt == 0) ? acc0 : (mt == 1) ? acc1 : acc2;
#pragma unroll
          for (int r = 0; r < 4; ++r) {
            const float v = acc[r];
            const _Float16 h = (_Float16)v;
            Uh[(r0 + r) * 72 + cc] = h;
            Ul[(r0 + r) * 72 + cc] = (_Float16)(v - (float)h);
          }
        }
      }
    }

    // PIPELINE: issue next slab's X loads now — they stay in flight across
    // GEMM2 + D2 dump + epilogue (the formerly load-dead 2/3 of the chain).
    if (it < 5) load_xf(xc + (size_t)(n1 + 1) * 2304, c16, kb, nxt);

    // ---- GEMM2: D2 = U * T2t, 9 output tiles in VGPRs ----
    // per-acc order identical to r20: ks0 {ah*t2h, ah*t2l, al*t2h} then ks1.
    f32x4 a2[3][3] = {};
#pragma unroll
    for (int ks = 0; ks < 2; ++ks) {
#pragma unroll
      for (int mt = 0; mt < 3; ++mt) {
        const half8 ah = *(const half8*)&Uh[(mt * 16 + c16) * 72 + ks * 32 + kb];
        const half8 al = *(const half8*)&Ul[(mt * 16 + c16) * 72 + ks * 32 + kb];
#pragma unroll
        for (int nt2 = 0; nt2 < 3; ++nt2) {
          a2[mt][nt2] = __builtin_amdgcn_mfma_f32_16x16x32_f16(ah, t2h[nt2][ks], a2[mt][nt2], 0, 0, 0);
          a2[mt][nt2] = __builtin_amdgcn_mfma_f32_16x16x32_f16(ah, t2l[nt2][ks], a2[mt][nt2], 0, 0, 0);
          a2[mt][nt2] = __builtin_amdgcn_mfma_f32_16x16x32_f16(al, t2h[nt2][ks], a2[mt][nt2], 0, 0, 0);
        }
      }
    }

    // D2 dump overlaying the arena (U reads all issued; DS in-order per wave)
#pragma unroll
    for (int mt = 0; mt < 3; ++mt)
#pragma unroll
      for (int nt2 = 0; nt2 < 3; ++nt2) {
        const int r0 = mt * 16 + kgrp * 4;
        const int cc = nt2 * 16 + c16;
#pragma unroll
        for (int r = 0; r < 4; ++r)
          D2[(r0 + r) * 68 + cc] = a2[mt][nt2][r];
      }

    // epilogue: recombine -> V[bc][k3][n1][k2] (576 float2; 9 per lane)
#pragma unroll
    for (int q = 0; q < 9; ++q) {
      const int idx = lane + 64 * q;          // 0..575
      const int k3 = idx / 24, k2 = idx % 24;
      const float grr = D2[k3 * 68 + k2];
      const float gis = D2[(k3 + 24) * 68 + k2 + 24];
      const float gir = D2[(k3 + 24) * 68 + k2];
      const float grs = D2[k3 * 68 + k2 + 24];
      V[(size_t)bc * 27648 + (size_t)k3 * 1152 + n1 * 24 + k2] =
          make_float2(grr + gis, gir - grs);
    }

    // re-zero U pads (D2 overlay clobbered them); ordered after epilogue D2-reads
    // and before next slab's GEMM2 pad-reads by per-wave DS program order.
    if (it < 5) {
#pragma unroll
      for (int p = 0; p < 3; ++p) {
        const int i = lane + 64 * p;
        const int which = i / 48, r = i % 48;
        _Float16* base = (which & 2) ? Ul : Uh;
        *(half8*)&base[r * 72 + 48 + (which & 1) * 8] = (half8){};
      }
    }
  }
}

// ---------------- K2: A3+B1 fused MFMA GEMM (192 thr, grid 24 x 64, 2 bc-pairs/block) ----------------
// Writes W[bc][m1][k3][k2] (separate buffer, m1-major) so K3 reads are contiguous.
__global__ __launch_bounds__(192) void k2_mfma(const float2* __restrict__ V,
                                               float2* __restrict__ W) {
  const int k3   = blockIdx.x;    // 0..23
  const int byy  = blockIdx.y;    // 0..63 -> bcp = byy*2+g
  const int tid  = threadIdx.x;
  const int lane = tid & 63;
  const int w    = tid >> 6;      // 0..2

  __shared__ __align__(16) float Bb[48 * 100];  // [col=s*24+k2][kap 0..95]

  half8 kth[4][3], ktl[4][3];
#pragma unroll
  for (int mt = 0; mt < 4; ++mt)
#pragma unroll
    for (int ks = 0; ks < 3; ++ks) {
      kth[mt][ks] = *(const half8*)&TK2frag[0][mt][ks][lane][0];
      ktl[mt][ks] = *(const half8*)&TK2frag[1][mt][ks][lane][0];
    }

  const int kbase = (lane >> 4) * 8;
  const int c16   = lane & 15;
  const int cc    = w * 16 + c16;       // 0..47
  const int sE    = cc / 24, k2E = cc % 24;
  const int rbase = (lane >> 4) * 4;

  // prologue prefetch (g=0): 6 float4/thread; s = jj/3, r = tid + 192*(jj%3)
  float4 vr[6];
  {
    const float4* g0 = (const float4*)(V + ((size_t)((byy * 4 + 0) * 24 + k3)) * 1152);
    const float4* g1 = (const float4*)(V + ((size_t)((byy * 4 + 1) * 24 + k3)) * 1152);
#pragma unroll
    for (int jj = 0; jj < 6; ++jj)
      vr[jj] = (jj < 3 ? g0 : g1)[tid + 192 * (jj % 3)];
  }

  for (int g = 0; g < 2; ++g) {
    const int bcp = byy * 2 + g;

    if (g) __syncthreads();   // prev iteration's Bb reads done

    // stage from prefetched regs
#pragma unroll
    for (int jj = 0; jj < 6; ++jj) {
      const int s = jj / 3;
      const int r = tid + 192 * (jj % 3);     // 0..575 within slab
      const int n1 = r / 12, c4 = r % 12;
      const float4 f = vr[jj];
      float* bp = &Bb[(s * 24 + c4 * 2) * 100 + n1];
      bp[0]   = f.x;  bp[48]  = f.y;
      bp[100] = f.z;  bp[148] = f.w;
    }
    // prefetch next bc-pair
    if (g < 1) {
      const float4* g0 = (const float4*)(V + ((size_t)((bcp * 2 + 2) * 24 + k3)) * 1152);
      const float4* g1 = (const float4*)(V + ((size_t)((bcp * 2 + 3) * 24 + k3)) * 1152);
#pragma unroll
      for (int jj = 0; jj < 6; ++jj)
        vr[jj] = (jj < 3 ? g0 : g1)[tid + 192 * (jj % 3)];
    }
    __syncthreads();

    f32x4 a0 = {}, a1 = {}, a2 = {}, a3 = {};
#pragma unroll
    for (int ks = 0; ks < 3; ++ks) {
      const float4 q0 = *(const float4*)&Bb[cc * 100 + ks * 32 + kbase];
      const float4 q1 = *(const float4*)&Bb[cc * 100 + ks * 32 + kbase + 4];
      const float qf[8] = {q0.x, q0.y, q0.z, q0.w, q1.x, q1.y, q1.z, q1.w};
      half8 bh, bl;
      split8(qf, bh, bl);
#pragma unroll
      for (int mt = 0; mt < 4; ++mt) {
        f32x4& acc = (mt == 0) ? a0 : (mt == 1) ? a1 : (mt == 2) ? a2 : a3;
        acc = __builtin_amdgcn_mfma_f32_16x16x32_f16(kth[mt][ks], bh, acc, 0, 0, 0);
        acc = __builtin_amdgcn_mfma_f32_16x16x32_f16(kth[mt][ks], bl, acc, 0, 0, 0);
        acc = __builtin_amdgcn_mfma_f32_16x16x32_f16(ktl[mt][ks], bh, acc, 0, 0, 0);
      }
    }

    // epilogue: rows 0..31 = Wr, rows 32..63 = Wi -> W[bc][m1][k3][k2]
    const int bc = bcp * 2 + sE;
    float2* wp = W + (size_t)bc * 18432 + (size_t)k3 * 24 + k2E;
#pragma unroll
    for (int mt = 0; mt < 2; ++mt) {
      const f32x4 wr = (mt == 0) ? a0 : a1;
      const f32x4 wi = (mt == 0) ? a2 : a3;
#pragma unroll
      for (int r = 0; r < 4; ++r) {
        const int m1 = mt * 16 + rbase + r;
        wp[(size_t)m1 * 576] = make_float2(wr[r], wi[r]);
      }
    }
  }
}

// ---------------- K3: B2 + B3 chained MFMA (128 thr, grid 32 x 128, 2 bc/block) ----------------
// Reads W[bc][m1][k3][k2]: 288 contiguous float4 per (bc,m1).
// Race audit: stage(g) writes Bt; readers GEMM1(g-1) all pre-b2(g-1). relayout(g)
// writes Zb; readers GEMM2(g-1) all pre-b1(g). GEMM2(g) reads Zb written pre-b2(g).
__global__ __launch_bounds__(128) void k3_mfma(const float2* __restrict__ W,
                                               float* __restrict__ out) {
  const int m1   = blockIdx.x;   // 0..31
  const int byy  = blockIdx.y;   // 0..127 -> bc = byy*2+g
  const int tid  = threadIdx.x;
  const int lane = tid & 63;
  const int w    = tid >> 6;     // 0..1

  __shared__ __align__(16) float Bt[32 * 68];   // [col=k3][kap: k2|24+k2|pad]
  __shared__ __align__(16) float Zb[32 * 68];   // [m2][kap: k3|24+k3|pad]

  half8 mbh[4][2], mbl[4][2];
#pragma unroll
  for (int mt = 0; mt < 4; ++mt)
#pragma unroll
    for (int ks = 0; ks < 2; ++ks) {
      mbh[mt][ks] = *(const half8*)&MB2frag[0][mt][ks][lane][0];
      mbl[mt][ks] = *(const half8*)&MB2frag[1][mt][ks][lane][0];
    }
  half8 tb3h[2], tb3l[2];
#pragma unroll
  for (int ks = 0; ks < 2; ++ks) {
    tb3h[ks] = *(const half8*)&TB3frag[0][w][ks][lane][0];
    tb3l[ks] = *(const half8*)&TB3frag[1][w][ks][lane][0];
  }

  // zero pad regions ONCE (data writes never touch them)
  for (int i = tid; i < 8 * 68; i += 128)  Bt[(24 + i / 68) * 68 + (i % 68)] = 0.f;
  for (int i = tid; i < 24 * 20; i += 128) Bt[(i / 20) * 68 + 48 + (i % 20)] = 0.f;
  for (int i = tid; i < 32 * 20; i += 128) Zb[(i / 20) * 68 + 48 + (i % 20)] = 0.f;

  const int kbase = (lane >> 4) * 8;
  const int c16   = lane & 15;
  const int cc    = w * 16 + c16;
  const int rbase = (lane >> 4) * 4;

  // prologue prefetch (g=0): 288 contiguous float4 (jj=2 only tid<32)
  float4 vr0, vr1, vr2;
  {
    const float4* g4 = (const float4*)(W + (size_t)(byy * 2) * 18432 + (size_t)m1 * 576);
    vr0 = g4[tid];
    vr1 = g4[tid + 128];
    if (tid < 32) vr2 = g4[tid + 256];
  }

  for (int g = 0; g < 2; ++g) {
    const int bc = byy * 2 + g;

    // stage Bt from prefetched regs
    {
      const float4 fr[3] = {vr0, vr1, vr2};
#pragma unroll
      for (int jj = 0; jj < 3; ++jj) {
        const int i4 = tid + 128 * jj;
        if (jj < 2 || tid < 32) {
          const int k3 = i4 / 12, c4 = i4 % 12;
          const float4 f = fr[jj];
          Bt[k3 * 68 + 2 * c4]          = f.x;
          Bt[k3 * 68 + 24 + 2 * c4]     = f.y;
          Bt[k3 * 68 + 2 * c4 + 1]      = f.z;
          Bt[k3 * 68 + 24 + 2 * c4 + 1] = f.w;
        }
      }
    }
    // prefetch next bc
    if (g < 1) {
      const float4* g4 = (const float4*)(W + (size_t)(bc + 1) * 18432 + (size_t)m1 * 576);
      vr0 = g4[tid];
      vr1 = g4[tid + 128];
      if (tid < 32) vr2 = g4[tid + 256];
    }
    __syncthreads();   // b1: Bt staged (and prev GEMM2's Zb reads done)

    // GEMM1: [Zr;Zi](64 x k3) = MB2 * [Wr;Wi]
    f32x4 z0 = {}, z1 = {}, z2 = {}, z3 = {};
#pragma unroll
    for (int ks = 0; ks < 2; ++ks) {
      const float4 q0 = *(const float4*)&Bt[cc * 68 + ks * 32 + kbase];
      const float4 q1 = *(const float4*)&Bt[cc * 68 + ks * 32 + kbase + 4];
      const float qf[8] = {q0.x, q0.y, q0.z, q0.w, q1.x, q1.y, q1.z, q1.w};
      half8 bh, bl;
      split8(qf, bh, bl);
#pragma unroll
      for (int mt = 0; mt < 4; ++mt) {
        f32x4& acc = (mt == 0) ? z0 : (mt == 1) ? z1 : (mt == 2) ? z2 : z3;
        acc = __builtin_amdgcn_mfma_f32_16x16x32_f16(mbh[mt][ks], bh, acc, 0, 0, 0);
        acc = __builtin_amdgcn_mfma_f32_16x16x32_f16(mbh[mt][ks], bl, acc, 0, 0, 0);
        acc = __builtin_amdgcn_mfma_f32_16x16x32_f16(mbl[mt][ks], bh, acc, 0, 0, 0);
      }
    }
    // relayout: Zb[m2][k3] = Zr, Zb[m2][24+k3] = Zi
    if (cc < 24) {
#pragma unroll
      for (int mt = 0; mt < 4; ++mt) {
        const f32x4 acc = (mt == 0) ? z0 : (mt == 1) ? z1 : (mt == 2) ? z2 : z3;
        const int row0 = mt * 16 + rbase;
#pragma unroll
        for (int r = 0; r < 4; ++r) {
          const int row = row0 + r;
          if (row < 32) Zb[row * 68 + cc]              = acc[r];
          else          Zb[(row - 32) * 68 + 24 + cc]  = acc[r];
        }
      }
    }
    __syncthreads();   // b2: Zb visible (and all Bt reads done)

    // GEMM2: out(32x32) = Z(32 x 48p64) * TB3
    f32x4 o0 = {}, o1 = {};
#pragma unroll
    for (int ks = 0; ks < 2; ++ks) {
#pragma unroll
      for (int mt = 0; mt < 2; ++mt) {
        const float4 q0 = *(const float4*)&Zb[(mt * 16 + c16) * 68 + ks * 32 + kbase];
        const float4 q1 = *(const float4*)&Zb[(mt * 16 + c16) * 68 + ks * 32 + kbase + 4];
        const float qf[8] = {q0.x, q0.y, q0.z, q0.w, q1.x, q1.y, q1.z, q1.w};
        half8 ah, al;
        split8(qf, ah, al);
        f32x4& acc = (mt == 0) ? o0 : o1;
        acc = __builtin_amdgcn_mfma_f32_16x16x32_f16(ah, tb3h[ks], acc, 0, 0, 0);
        acc = __builtin_amdgcn_mfma_f32_16x16x32_f16(ah, tb3l[ks], acc, 0, 0, 0);
        acc = __builtin_amdgcn_mfma_f32_16x16x32_f16(al, tb3h[ks], acc, 0, 0, 0);
      }
    }
    float* op = out + (size_t)(bc * 32 + m1) * 1024;
#pragma unroll
    for (int mt = 0; mt < 2; ++mt) {
      const f32x4 acc = (mt == 0) ? o0 : o1;
#pragma unroll
      for (int r = 0; r < 4; ++r) {
        const int m2 = mt * 16 + rbase + r;
        op[m2 * 32 + cc] = acc[r] * NORM_F;
      }
    }
  }

  // set lazy-init flag: runs strictly after k_init_tw in stream order, so the
  // NEXT kernel_launch's k_init_tw can safely early-exit (tables are pure consts).
  if (tid == 0 && blockIdx.x == 0 && blockIdx.y == 0) g_twdone = 1;
}

extern "C" void kernel_launch(void* const* d_in, const int* in_sizes, int n_in,
                              void* d_out, int out_size, void* d_ws, size_t ws_size,
                              hipStream_t stream) {
  const float* x = (const float*)d_in[0];
  float* out = (float*)d_out;
  float2* V = (float2*)d_ws;                                   // 56,623,104 B
  float2* W = (float2*)((char*)d_ws + 56623104);               // 37,748,736 B

  k_init_tw   <<<dim3(60), dim3(256), 0, stream>>>();
  k1_waveslab <<<dim3(8, 256), dim3(64), 0, stream>>>(x, V);
  k2_mfma     <<<dim3(24, 64), dim3(192), 0, stream>>>(V, W);
  k3_mfma     <<<dim3(32, 128), dim3(128), 0, stream>>>(W, out);
}

// Round 13
// 80.589 us; speedup vs baseline: 1.0069x; 1.0069x over previous
//
#include <hip/hip_runtime.h>
#include <math.h>

// SpectralPooling: out = Re(ifft3_32(pad32(crop24(Re(fft3_48(x))))))  per (b,c) volume.
// bc = 256 volumes of 48^3 fp32 -> 256 x 32^3 fp32.
//
// r22 = r20 (best, 79.2us) + DS-pressure attack:
//  (a) K1: U stored in LDS as f32 SINGLE-COPY [48][68] (same buffer D2 overlays,
//      same stride). U-dump 72 ds_write_b16 -> 36 ds_write_b32; GEMM2 reads two
//      aligned float4/frag + split8 at read time -> identical hi/lo values feed
//      the SAME MFMA sequence (bitwise-identical output). Arena 13824->13056 B.
//      Mechanism: K1's unmeasured DS pipe carries ~156 ops/slab (~1000 cyc) on the
//      serial GEMM1->GEMM2 chain shared by ~8 waves/CU; halving the dump cuts it.
//  (b) K2/K3: single tile per block (grid 24x128 / 32x256) - no per-block loops,
//      no double-buffer hazards, finer tail.
// K1 launch_bounds(64,3) kept (r20's win). MFMA per-accumulator order verbatim ->
// absmax must stay exactly 0.00390625.
//  K1 (per (bc,n1) wave, zero barriers): D1 = T1*X ; D2 = D1*T2t ; recombine -> V
//  K2 (per (k3,bcp)): [Wr;Wi](64x48) = M_comb(64x96) * [Vr;Vi](96x48) -> W
//  K3 (per (m1,bc)): [Zr;Zi] = MB2*[Wr;Wi] ; out = Z*TB3
// Split-f16 everywhere: P = Ahi*Bhi + Ahi*Blo + Alo*Bhi (~22 mantissa bits).
//
// d_ws: float2 V[256][24][48][24] (56,623,104 B) then
//       float2 W[256][32][24][24] (37,748,736 B) at byte offset 56,623,104.

#define TWO_PI_48 0.13089969389957470f
#define TWO_PI_32 0.19634954084936207f
#define NORM_F    1.6611664e-05f         // 1/(48^1.5 * 32^1.5)

typedef _Float16 half8  __attribute__((ext_vector_type(8)));
typedef _Float16 half4v __attribute__((ext_vector_type(4)));
typedef float    f32x4  __attribute__((ext_vector_type(4)));

// Frag-layout tables: [hi/lo][tile][kstep][lane][j]
// A-frag element = A[tile*16 + (l&15)][ks*32 + (l>>4)*8 + j]
// B-frag element = B[ks*32 + (l>>4)*8 + j][tile*16 + (l&15)]
__device__ _Float16 T1frag[2][3][2][64][8];
__device__ _Float16 T2frag[2][3][2][64][8];
__device__ __align__(16) _Float16 TK2frag[2][4][3][64][8];  // M_comb 64x96
__device__ __align__(16) _Float16 MB2frag[2][4][2][64][8];  // 64x48 (pad 64)
__device__ __align__(16) _Float16 TB3frag[2][2][2][64][8];  // 48(pad64)x32

__device__ int g_twdone = 0;   // lazy-init flag (module-lifetime, set post-init)

__global__ void k_init_tw() {
  if (g_twdone) return;                             // tables already built (pure consts)
  const int idx = blockIdx.x * 256 + threadIdx.x;   // 0..15359
  if (idx < 3072) {                                 // K1 tables (verified r5)
    const int j  = idx & 7;
    const int l  = (idx >> 3) & 63;
    const int ks = (idx >> 9) & 1;
    const int t  = idx >> 10;
    const int k  = ks * 32 + (l >> 4) * 8 + j;
    {
      const int m = t * 16 + (l & 15);
      float v = 0.f;
      if (k < 48) {
        const float a = (float)(((m % 24) * k) % 48) * TWO_PI_48;
        v = (m < 24) ? cosf(a) : -sinf(a);
      }
      const _Float16 h = (_Float16)v;
      T1frag[0][t][ks][l][j] = h;
      T1frag[1][t][ks][l][j] = (_Float16)(v - (float)h);
    }
    {
      const int c = t * 16 + (l & 15);
      float v = 0.f;
      if (k < 48) {
        const float a = (float)(((c % 24) * k) % 48) * TWO_PI_48;
        v = (c < 24) ? cosf(a) : sinf(a);
      }
      const _Float16 h = (_Float16)v;
      T2frag[0][t][ks][l][j] = h;
      T2frag[1][t][ks][l][j] = (_Float16)(v - (float)h);
    }
  } else if (idx < 3072 + 6144) {                   // K2: M_comb (A3+B1 fused)
    const int local = idx - 3072;
    const int j = local & 7, l = (local >> 3) & 63;
    const int rest = local >> 9;                    // 0..11
    const int ks = rest % 3, mt = rest / 3;
    const int m   = mt * 16 + (l & 15);             // 0..63
    const int kap = ks * 32 + (l >> 4) * 8 + j;     // 0..95
    const int n1  = kap % 48;
    const bool isVi = kap >= 48;
    const int m1  = m & 31;
    const bool isWi = m >= 32;
    float acc = 0.f;
    for (int k1 = 0; k1 < 24; ++k1) {
      float s32v, c32v, s48v, c48v;
      sincosf((float)((k1 * m1) % 32) * TWO_PI_32, &s32v, &c32v);
      sincosf((float)((k1 * n1) % 48) * TWO_PI_48, &s48v, &c48v);
      acc = fmaf(isWi ? s32v : c32v, isVi ? s48v : c48v, acc);
    }
    const _Float16 h = (_Float16)acc;
    TK2frag[0][mt][ks][l][j] = h;
    TK2frag[1][mt][ks][l][j] = (_Float16)(acc - (float)h);
  } else if (idx < 3072 + 6144 + 4096) {            // K3: MB2 (B2 A-matrix)
    const int local = idx - (3072 + 6144);
    const int j = local & 7, l = (local >> 3) & 63;
    const int rest = local >> 9;                    // 0..7
    const int ks = rest & 1, mt = rest >> 1;
    const int m   = mt * 16 + (l & 15);             // 0..63
    const int kap = ks * 32 + (l >> 4) * 8 + j;     // 0..63
    float v = 0.f;
    if (kap < 48) {
      const int k2 = kap % 24;
      const int m2 = m & 31;
      float s, c;
      sincosf((float)((k2 * m2) % 32) * TWO_PI_32, &s, &c);
      if (m < 32) v = (kap < 24) ? c : -s;   // Zr = sum Wr*c - Wi*s
      else        v = (kap < 24) ? s :  c;   // Zi = sum Wr*s + Wi*c
    }
    const _Float16 h = (_Float16)v;
    MB2frag[0][mt][ks][l][j] = h;
    MB2frag[1][mt][ks][l][j] = (_Float16)(v - (float)h);
  } else if (idx < 15360) {                         // K3: TB3 (B3 B-matrix)
    const int local = idx - (3072 + 6144 + 4096);
    const int j = local & 7, l = (local >> 3) & 63;
    const int rest = local >> 9;                    // 0..3
    const int ks = rest & 1, nt = rest >> 1;
    const int m3  = nt * 16 + (l & 15);             // col 0..31
    const int kap = ks * 32 + (l >> 4) * 8 + j;     // 0..63
    float v = 0.f;
    if (kap < 48) {
      const int k3 = kap % 24;
      float s, c;
      sincosf((float)((k3 * m3) % 32) * TWO_PI_32, &s, &c);
      v = (kap < 24) ? c : -s;               // out = sum Zr*c - Zi*s
    }
    const _Float16 h = (_Float16)v;
    TB3frag[0][nt][ks][l][j] = h;
    TB3frag[1][nt][ks][l][j] = (_Float16)(v - (float)h);
  }
}

__device__ inline void split8(const float* qf, half8& h, half8& lo) {
#pragma unroll
  for (int j = 0; j < 8; ++j) {
    const _Float16 hh = (_Float16)qf[j];
    h[j]  = hh;
    lo[j] = (_Float16)(qf[j] - (float)hh);
  }
}

// ---------------- K1: wave-slab, 64 thr, grid 48 x 256, ZERO barriers ----------------
// LDS: float U[48][68] (13056 B). U data cols 0..47, zero pad cols 48..63 (GEMM2
// A-frags read k up to 63). D2 f32 [48][68] OVERLAYS the same buffer after GEMM2
// (U dead; DS pipe in-order per wave). U stored f32 single-copy; hi/lo split done
// at READ time -> identical values feed the same MFMA sequence as r20.
// launch_bounds(64,3): VGPR cap ~170 (r20's win).
__global__ __launch_bounds__(64, 3) void k1_waveslab(const float* __restrict__ x,
                                                     float2* __restrict__ V) {
  const int n1   = blockIdx.x;   // 0..47
  const int bc   = blockIdx.y;   // 0..255
  const int lane = threadIdx.x;  // 0..63

  __shared__ __align__(16) float U[48 * 68];   // also D2 view (stride 68)
  float* D2 = U;

  const int c16  = lane & 15;
  const int kgrp = lane >> 4;    // 0..3
  const int kb   = kgrp * 8;

  // twiddle fragments (all tiles; this wave does the whole slab)
  half8 t1h[3][2], t1l[3][2], t2h[3][2], t2l[3][2];
#pragma unroll
  for (int mt = 0; mt < 3; ++mt)
#pragma unroll
    for (int ks = 0; ks < 2; ++ks) {
      t1h[mt][ks] = *(const half8*)&T1frag[0][mt][ks][lane][0];
      t1l[mt][ks] = *(const half8*)&T1frag[1][mt][ks][lane][0];
      t2h[mt][ks] = *(const half8*)&T2frag[0][mt][ks][lane][0];
      t2l[mt][ks] = *(const half8*)&T2frag[1][mt][ks][lane][0];
    }

  // zero U pad cols 48..63 (192 float4 over 64 lanes; 16B-aligned: 68*4=272, 48*4,
  // c4*16 all 16-mults). Data dump touches cols 0..47 only -> disjoint.
#pragma unroll
  for (int p = 0; p < 3; ++p) {
    const int fl = lane + 64 * p;           // 0..191
    const int row = fl >> 2, c4 = fl & 3;
    *(f32x4*)&U[row * 68 + 48 + c4 * 4] = (f32x4){};
  }

  const float* xs = x + (size_t)(bc * 48 + n1) * 2304;

  // ---- GEMM1: D1 = T1 * X, per col-tile nt; U dump after each nt ----
  // prefetch nt=0 fragments
  float4 fa0, fb0, fa1, fb1;                  // ks=0 / ks=1 fragment halves
  {
    const float4* p0 = (const float4*)(xs + c16 * 48 + kb);          // ks=0: k=kb<32
    fa0 = p0[0]; fb0 = p0[1];
    const int k1i = 32 + kb;
    if (k1i < 48) {
      const float4* p1 = (const float4*)(xs + c16 * 48 + k1i);
      fa1 = p1[0]; fb1 = p1[1];
    } else { fa1 = make_float4(0.f,0.f,0.f,0.f); fb1 = fa1; }
  }

#pragma unroll
  for (int nt = 0; nt < 3; ++nt) {
    // prefetch next nt
    float4 na0, nb0, na1, nb1;
    if (nt < 2) {
      const int c = (nt + 1) * 16 + c16;
      const float4* p0 = (const float4*)(xs + c * 48 + kb);
      na0 = p0[0]; nb0 = p0[1];
      const int k1i = 32 + kb;
      if (k1i < 48) {
        const float4* p1 = (const float4*)(xs + c * 48 + k1i);
        na1 = p1[0]; nb1 = p1[1];
      } else { na1 = make_float4(0.f,0.f,0.f,0.f); nb1 = na1; }
    }

    f32x4 acc0 = {}, acc1 = {}, acc2 = {};
#pragma unroll
    for (int ks = 0; ks < 2; ++ks) {
      const float4 qa = ks ? fa1 : fa0;
      const float4 qb = ks ? fb1 : fb0;
      const float qf[8] = {qa.x, qa.y, qa.z, qa.w, qb.x, qb.y, qb.z, qb.w};
      half8 bh, bl;
      split8(qf, bh, bl);
#pragma unroll
      for (int mt = 0; mt < 3; ++mt) {
        f32x4& acc = (mt == 0) ? acc0 : (mt == 1) ? acc1 : acc2;
        acc = __builtin_amdgcn_mfma_f32_16x16x32_f16(t1h[mt][ks], bh, acc, 0, 0, 0);
        acc = __builtin_amdgcn_mfma_f32_16x16x32_f16(t1h[mt][ks], bl, acc, 0, 0, 0);
        acc = __builtin_amdgcn_mfma_f32_16x16x32_f16(t1l[mt][ks], bh, acc, 0, 0, 0);
      }
    }

    // U dump for this nt: f32 single write per element (36 total vs r20's 72 b16)
    {
      const int cc = nt * 16 + c16;
#pragma unroll
      for (int mt = 0; mt < 3; ++mt) {
        const int r0 = mt * 16 + kgrp * 4;
        const f32x4 acc = (mt == 0) ? acc0 : (mt == 1) ? acc1 : acc2;
#pragma unroll
        for (int r = 0; r < 4; ++r)
          U[(r0 + r) * 68 + cc] = acc[r];
      }
    }

    fa0 = na0; fb0 = nb0; fa1 = na1; fb1 = nb1;
  }

  // ---- GEMM2: D2 = U * T2t, all 9 output tiles held in VGPRs ----
  // A-frag read: two aligned float4 from U row, split8 at read time -> identical
  // hi/lo values as r20's stored pair; per-acc order identical (ks0 {h*t2h, h*t2l,
  // l*t2h} then ks1).
  f32x4 a2[3][3] = {};   // [mt][nt2], fully unrolled indices (static)
#pragma unroll
  for (int ks = 0; ks < 2; ++ks) {
#pragma unroll
    for (int mt = 0; mt < 3; ++mt) {
      const float4 q0 = *(const float4*)&U[(mt * 16 + c16) * 68 + ks * 32 + kb];
      const float4 q1 = *(const float4*)&U[(mt * 16 + c16) * 68 + ks * 32 + kb + 4];
      const float qf[8] = {q0.x, q0.y, q0.z, q0.w, q1.x, q1.y, q1.z, q1.w};
      half8 ah, al;
      split8(qf, ah, al);
#pragma unroll
      for (int nt2 = 0; nt2 < 3; ++nt2) {
        a2[mt][nt2] = __builtin_amdgcn_mfma_f32_16x16x32_f16(ah, t2h[nt2][ks], a2[mt][nt2], 0, 0, 0);
        a2[mt][nt2] = __builtin_amdgcn_mfma_f32_16x16x32_f16(ah, t2l[nt2][ks], a2[mt][nt2], 0, 0, 0);
        a2[mt][nt2] = __builtin_amdgcn_mfma_f32_16x16x32_f16(al, t2h[nt2][ks], a2[mt][nt2], 0, 0, 0);
      }
    }
  }

  // D2 dump overlaying U (all U reads issued above; DS pipe in-order per wave,
  // aliasing visible through the shared buffer).
#pragma unroll
  for (int mt = 0; mt < 3; ++mt)
#pragma unroll
    for (int nt2 = 0; nt2 < 3; ++nt2) {
      const int r0 = mt * 16 + kgrp * 4;
      const int cc = nt2 * 16 + c16;
#pragma unroll
      for (int r = 0; r < 4; ++r)
        D2[(r0 + r) * 68 + cc] = a2[mt][nt2][r];
    }

  // epilogue: recombine -> V[bc][k3][n1][k2] (576 float2; 9 per lane)
#pragma unroll
  for (int q = 0; q < 9; ++q) {
    const int idx = lane + 64 * q;          // 0..575
    const int k3 = idx / 24, k2 = idx % 24;
    const float grr = D2[k3 * 68 + k2];
    const float gis = D2[(k3 + 24) * 68 + k2 + 24];
    const float gir = D2[(k3 + 24) * 68 + k2];
    const float grs = D2[k3 * 68 + k2 + 24];
    V[(size_t)bc * 27648 + (size_t)k3 * 1152 + n1 * 24 + k2] =
        make_float2(grr + gis, gir - grs);
  }
}

// ---------------- K2: A3+B1 fused MFMA GEMM (192 thr, grid 24 x 128, 1 bc-pair/block) ----------------
// Writes W[bc][m1][k3][k2] (separate buffer, m1-major) so K3 reads are contiguous.
__global__ __launch_bounds__(192) void k2_mfma(const float2* __restrict__ V,
                                               float2* __restrict__ W) {
  const int k3   = blockIdx.x;    // 0..23
  const int bcp  = blockIdx.y;    // 0..127
  const int tid  = threadIdx.x;
  const int lane = tid & 63;
  const int w    = tid >> 6;      // 0..2

  __shared__ __align__(16) float Bb[48 * 100];  // [col=s*24+k2][kap 0..95]

  half8 kth[4][3], ktl[4][3];
#pragma unroll
  for (int mt = 0; mt < 4; ++mt)
#pragma unroll
    for (int ks = 0; ks < 3; ++ks) {
      kth[mt][ks] = *(const half8*)&TK2frag[0][mt][ks][lane][0];
      ktl[mt][ks] = *(const half8*)&TK2frag[1][mt][ks][lane][0];
    }

  const int kbase = (lane >> 4) * 8;
  const int c16   = lane & 15;
  const int cc    = w * 16 + c16;       // 0..47
  const int sE    = cc / 24, k2E = cc % 24;
  const int rbase = (lane >> 4) * 4;

  // prefetch: 6 float4/thread; s = jj/3, r = tid + 192*(jj%3)
  float4 vr[6];
  {
    const float4* g0 = (const float4*)(V + ((size_t)((bcp * 2 + 0) * 24 + k3)) * 1152);
    const float4* g1 = (const float4*)(V + ((size_t)((bcp * 2 + 1) * 24 + k3)) * 1152);
#pragma unroll
    for (int jj = 0; jj < 6; ++jj)
      vr[jj] = (jj < 3 ? g0 : g1)[tid + 192 * (jj % 3)];
  }

  // stage from prefetched regs
#pragma unroll
  for (int jj = 0; jj < 6; ++jj) {
    const int s = jj / 3;
    const int r = tid + 192 * (jj % 3);     // 0..575 within slab
    const int n1 = r / 12, c4 = r % 12;
    const float4 f = vr[jj];
    float* bp = &Bb[(s * 24 + c4 * 2) * 100 + n1];
    bp[0]   = f.x;  bp[48]  = f.y;
    bp[100] = f.z;  bp[148] = f.w;
  }
  __syncthreads();

  f32x4 a0 = {}, a1 = {}, a2 = {}, a3 = {};
#pragma unroll
  for (int ks = 0; ks < 3; ++ks) {
    const float4 q0 = *(const float4*)&Bb[cc * 100 + ks * 32 + kbase];
    const float4 q1 = *(const float4*)&Bb[cc * 100 + ks * 32 + kbase + 4];
    const float qf[8] = {q0.x, q0.y, q0.z, q0.w, q1.x, q1.y, q1.z, q1.w};
    half8 bh, bl;
    split8(qf, bh, bl);
#pragma unroll
    for (int mt = 0; mt < 4; ++mt) {
      f32x4& acc = (mt == 0) ? a0 : (mt == 1) ? a1 : (mt == 2) ? a2 : a3;
      acc = __builtin_amdgcn_mfma_f32_16x16x32_f16(kth[mt][ks], bh, acc, 0, 0, 0);
      acc = __builtin_amdgcn_mfma_f32_16x16x32_f16(kth[mt][ks], bl, acc, 0, 0, 0);
      acc = __builtin_amdgcn_mfma_f32_16x16x32_f16(ktl[mt][ks], bh, acc, 0, 0, 0);
    }
  }

  // epilogue: rows 0..31 = Wr, rows 32..63 = Wi -> W[bc][m1][k3][k2]
  const int bc = bcp * 2 + sE;
  float2* wp = W + (size_t)bc * 18432 + (size_t)k3 * 24 + k2E;
#pragma unroll
  for (int mt = 0; mt < 2; ++mt) {
    const f32x4 wr = (mt == 0) ? a0 : a1;
    const f32x4 wi = (mt == 0) ? a2 : a3;
#pragma unroll
    for (int r = 0; r < 4; ++r) {
      const int m1 = mt * 16 + rbase + r;
      wp[(size_t)m1 * 576] = make_float2(wr[r], wi[r]);
    }
  }
}

// ---------------- K3: B2 + B3 chained MFMA (128 thr, grid 32 x 256, 1 bc/block) ----------------
// Reads W[bc][m1][k3][k2]: 288 contiguous float4 per (bc,m1).
// Barriers: pads+stage -> b1 -> GEMM1+relayout(Zb) -> b2 -> GEMM2+store.
__global__ __launch_bounds__(128) void k3_mfma(const float2* __restrict__ W,
                                               float* __restrict__ out) {
  const int m1   = blockIdx.x;   // 0..31
  const int bc   = blockIdx.y;   // 0..255
  const int tid  = threadIdx.x;
  const int lane = tid & 63;
  const int w    = tid >> 6;     // 0..1

  __shared__ __align__(16) float Bt[32 * 68];   // [col=k3][kap: k2|24+k2|pad]
  __shared__ __align__(16) float Zb[32 * 68];   // [m2][kap: k3|24+k3|pad]

  half8 mbh[4][2], mbl[4][2];
#pragma unroll
  for (int mt = 0; mt < 4; ++mt)
#pragma unroll
    for (int ks = 0; ks < 2; ++ks) {
      mbh[mt][ks] = *(const half8*)&MB2frag[0][mt][ks][lane][0];
      mbl[mt][ks] = *(const half8*)&MB2frag[1][mt][ks][lane][0];
    }
  half8 tb3h[2], tb3l[2];
#pragma unroll
  for (int ks = 0; ks < 2; ++ks) {
    tb3h[ks] = *(const half8*)&TB3frag[0][w][ks][lane][0];
    tb3l[ks] = *(const half8*)&TB3frag[1][w][ks][lane][0];
  }

  // zero pad regions (fenced by b1)
  for (int i = tid; i < 8 * 68; i += 128)  Bt[(24 + i / 68) * 68 + (i % 68)] = 0.f;
  for (int i = tid; i < 24 * 20; i += 128) Bt[(i / 20) * 68 + 48 + (i % 20)] = 0.f;
  for (int i = tid; i < 32 * 20; i += 128) Zb[(i / 20) * 68 + 48 + (i % 20)] = 0.f;

  const int kbase = (lane >> 4) * 8;
  const int c16   = lane & 15;
  const int cc    = w * 16 + c16;
  const int rbase = (lane >> 4) * 4;

  // prefetch: 288 contiguous float4 (jj=2 only tid<32)
  float4 vr0, vr1, vr2;
  {
    const float4* g4 = (const float4*)(W + (size_t)bc * 18432 + (size_t)m1 * 576);
    vr0 = g4[tid];
    vr1 = g4[tid + 128];
    if (tid < 32) vr2 = g4[tid + 256];
  }

  // stage Bt from prefetched regs
  {
    const float4 fr[3] = {vr0, vr1, vr2};
#pragma unroll
    for (int jj = 0; jj < 3; ++jj) {
      const int i4 = tid + 128 * jj;
      if (jj < 2 || tid < 32) {
        const int k3 = i4 / 12, c4 = i4 % 12;
        const float4 f = fr[jj];
        Bt[k3 * 68 + 2 * c4]          = f.x;
        Bt[k3 * 68 + 24 + 2 * c4]     = f.y;
        Bt[k3 * 68 + 2 * c4 + 1]      = f.z;
        Bt[k3 * 68 + 24 + 2 * c4 + 1] = f.w;
      }
    }
  }
  __syncthreads();   // b1: Bt staged, pads zeroed

  // GEMM1: [Zr;Zi](64 x k3) = MB2 * [Wr;Wi]
  f32x4 z0 = {}, z1 = {}, z2 = {}, z3 = {};
#pragma unroll
  for (int ks = 0; ks < 2; ++ks) {
    const float4 q0 = *(const float4*)&Bt[cc * 68 + ks * 32 + kbase];
    const float4 q1 = *(const float4*)&Bt[cc * 68 + ks * 32 + kbase + 4];
    const float qf[8] = {q0.x, q0.y, q0.z, q0.w, q1.x, q1.y, q1.z, q1.w};
    half8 bh, bl;
    split8(qf, bh, bl);
#pragma unroll
    for (int mt = 0; mt < 4; ++mt) {
      f32x4& acc = (mt == 0) ? z0 : (mt == 1) ? z1 : (mt == 2) ? z2 : z3;
      acc = __builtin_amdgcn_mfma_f32_16x16x32_f16(mbh[mt][ks], bh, acc, 0, 0, 0);
      acc = __builtin_amdgcn_mfma_f32_16x16x32_f16(mbh[mt][ks], bl, acc, 0, 0, 0);
      acc = __builtin_amdgcn_mfma_f32_16x16x32_f16(mbl[mt][ks], bh, acc, 0, 0, 0);
    }
  }
  // relayout: Zb[m2][k3] = Zr, Zb[m2][24+k3] = Zi
  if (cc < 24) {
#pragma unroll
    for (int mt = 0; mt < 4; ++mt) {
      const f32x4 acc = (mt == 0) ? z0 : (mt == 1) ? z1 : (mt == 2) ? z2 : z3;
      const int row0 = mt * 16 + rbase;
#pragma unroll
      for (int r = 0; r < 4; ++r) {
        const int row = row0 + r;
        if (row < 32) Zb[row * 68 + cc]              = acc[r];
        else          Zb[(row - 32) * 68 + 24 + cc]  = acc[r];
      }
    }
  }
  __syncthreads();   // b2: Zb visible

  // GEMM2: out(32x32) = Z(32 x 48p64) * TB3
  f32x4 o0 = {}, o1 = {};
#pragma unroll
  for (int ks = 0; ks < 2; ++ks) {
#pragma unroll
    for (int mt = 0; mt < 2; ++mt) {
      const float4 q0 = *(const float4*)&Zb[(mt * 16 + c16) * 68 + ks * 32 + kbase];
      const float4 q1 = *(const float4*)&Zb[(mt * 16 + c16) * 68 + ks * 32 + kbase + 4];
      const float qf[8] = {q0.x, q0.y, q0.z, q0.w, q1.x, q1.y, q1.z, q1.w};
      half8 ah, al;
      split8(qf, ah, al);
      f32x4& acc = (mt == 0) ? o0 : o1;
      acc = __builtin_amdgcn_mfma_f32_16x16x32_f16(ah, tb3h[ks], acc, 0, 0, 0);
      acc = __builtin_amdgcn_mfma_f32_16x16x32_f16(ah, tb3l[ks], acc, 0, 0, 0);
      acc = __builtin_amdgcn_mfma_f32_16x16x32_f16(al, tb3h[ks], acc, 0, 0, 0);
    }
  }
  float* op = out + (size_t)(bc * 32 + m1) * 1024;
#pragma unroll
  for (int mt = 0; mt < 2; ++mt) {
    const f32x4 acc = (mt == 0) ? o0 : o1;
#pragma unroll
    for (int r = 0; r < 4; ++r) {
      const int m2 = mt * 16 + rbase + r;
      op[m2 * 32 + cc] = acc[r] * NORM_F;
    }
  }

  // set lazy-init flag: runs strictly after k_init_tw in stream order, so the
  // NEXT kernel_launch's k_init_tw can safely early-exit (tables are pure consts).
  if (tid == 0 && blockIdx.x == 0 && blockIdx.y == 0) g_twdone = 1;
}

extern "C" void kernel_launch(void* const* d_in, const int* in_sizes, int n_in,
                              void* d_out, int out_size, void* d_ws, size_t ws_size,
                              hipStream_t stream) {
  const float* x = (const float*)d_in[0];
  float* out = (float*)d_out;
  float2* V = (float2*)d_ws;                                   // 56,623,104 B
  float2* W = (float2*)((char*)d_ws + 56623104);               // 37,748,736 B

  k_init_tw   <<<dim3(60), dim3(256), 0, stream>>>();
  k1_waveslab <<<dim3(48, 256), dim3(64), 0, stream>>>(x, V);
  k2_mfma     <<<dim3(24, 128), dim3(192), 0, stream>>>(V, W);
  k3_mfma     <<<dim3(32, 256), dim3(128), 0, stream>>>(W, out);
}

// Round 14
// 77.518 us; speedup vs baseline: 1.0468x; 1.0396x over previous
//
#include <hip/hip_runtime.h>
#include <math.h>

// SpectralPooling: out = Re(ifft3_32(pad32(crop24(Re(fft3_48(x))))))  per (b,c) volume.
// bc = 256 volumes of 48^3 fp32 -> 256 x 32^3 fp32.
//
// r23 = r20 base + K1 repacked as 4 INDEPENDENT WAVES PER BLOCK (zero barriers kept).
// Evidence: K1 = 12288 one-wave blocks; at ~7 waves/CU that is ~7 rounds x ~7.4us =
// ~17k cycles per slab-round vs ~2-3k cycles of actual chain work -> the invariant
// across ALL K1 variants (r16-r22, every one ~52-55us) is the 12288-block dispatch
// count. 4 waves/block: 3072 blocks (4x fewer dispatches), LDS 4x13056=52.2KB ->
// 3 blocks/CU = 12 waves/CU (also raises occupancy from ~7-8). launch_bounds(256,3)
// keeps r20's proven VGPR cap. Per-wave slab code = r22's verified single-copy-U
// body (read-time split8, bit-identical numerics). K2/K3/init verbatim r20.
// absmax must stay exactly 0.00390625.
//  K1 (4 waves/block, each owns one (bc,n1) slab): D1 = T1*X ; D2 = D1*T2t ; -> V
//  K2 (per k3, 2x bc-pair): [Wr;Wi](64x48) = M_comb(64x96) * [Vr;Vi](96x48) -> W
//  K3 (per m1, 2x bc): [Zr;Zi] = MB2*[Wr;Wi] ; out = Z*TB3
// Split-f16 everywhere: P = Ahi*Bhi + Ahi*Blo + Alo*Bhi (~22 mantissa bits).
//
// d_ws: float2 V[256][24][48][24] (56,623,104 B) then
//       float2 W[256][32][24][24] (37,748,736 B) at byte offset 56,623,104.

#define TWO_PI_48 0.13089969389957470f
#define TWO_PI_32 0.19634954084936207f
#define NORM_F    1.6611664e-05f         // 1/(48^1.5 * 32^1.5)

typedef _Float16 half8  __attribute__((ext_vector_type(8)));
typedef _Float16 half4v __attribute__((ext_vector_type(4)));
typedef float    f32x4  __attribute__((ext_vector_type(4)));

// Frag-layout tables: [hi/lo][tile][kstep][lane][j]
// A-frag element = A[tile*16 + (l&15)][ks*32 + (l>>4)*8 + j]
// B-frag element = B[ks*32 + (l>>4)*8 + j][tile*16 + (l&15)]
__device__ _Float16 T1frag[2][3][2][64][8];
__device__ _Float16 T2frag[2][3][2][64][8];
__device__ __align__(16) _Float16 TK2frag[2][4][3][64][8];  // M_comb 64x96
__device__ __align__(16) _Float16 MB2frag[2][4][2][64][8];  // 64x48 (pad 64)
__device__ __align__(16) _Float16 TB3frag[2][2][2][64][8];  // 48(pad64)x32

__device__ int g_twdone = 0;   // lazy-init flag (module-lifetime, set post-init)

__global__ void k_init_tw() {
  if (g_twdone) return;                             // tables already built (pure consts)
  const int idx = blockIdx.x * 256 + threadIdx.x;   // 0..15359
  if (idx < 3072) {                                 // K1 tables (verified r5)
    const int j  = idx & 7;
    const int l  = (idx >> 3) & 63;
    const int ks = (idx >> 9) & 1;
    const int t  = idx >> 10;
    const int k  = ks * 32 + (l >> 4) * 8 + j;
    {
      const int m = t * 16 + (l & 15);
      float v = 0.f;
      if (k < 48) {
        const float a = (float)(((m % 24) * k) % 48) * TWO_PI_48;
        v = (m < 24) ? cosf(a) : -sinf(a);
      }
      const _Float16 h = (_Float16)v;
      T1frag[0][t][ks][l][j] = h;
      T1frag[1][t][ks][l][j] = (_Float16)(v - (float)h);
    }
    {
      const int c = t * 16 + (l & 15);
      float v = 0.f;
      if (k < 48) {
        const float a = (float)(((c % 24) * k) % 48) * TWO_PI_48;
        v = (c < 24) ? cosf(a) : sinf(a);
      }
      const _Float16 h = (_Float16)v;
      T2frag[0][t][ks][l][j] = h;
      T2frag[1][t][ks][l][j] = (_Float16)(v - (float)h);
    }
  } else if (idx < 3072 + 6144) {                   // K2: M_comb (A3+B1 fused)
    const int local = idx - 3072;
    const int j = local & 7, l = (local >> 3) & 63;
    const int rest = local >> 9;                    // 0..11
    const int ks = rest % 3, mt = rest / 3;
    const int m   = mt * 16 + (l & 15);             // 0..63
    const int kap = ks * 32 + (l >> 4) * 8 + j;     // 0..95
    const int n1  = kap % 48;
    const bool isVi = kap >= 48;
    const int m1  = m & 31;
    const bool isWi = m >= 32;
    float acc = 0.f;
    for (int k1 = 0; k1 < 24; ++k1) {
      float s32v, c32v, s48v, c48v;
      sincosf((float)((k1 * m1) % 32) * TWO_PI_32, &s32v, &c32v);
      sincosf((float)((k1 * n1) % 48) * TWO_PI_48, &s48v, &c48v);
      acc = fmaf(isWi ? s32v : c32v, isVi ? s48v : c48v, acc);
    }
    const _Float16 h = (_Float16)acc;
    TK2frag[0][mt][ks][l][j] = h;
    TK2frag[1][mt][ks][l][j] = (_Float16)(acc - (float)h);
  } else if (idx < 3072 + 6144 + 4096) {            // K3: MB2 (B2 A-matrix)
    const int local = idx - (3072 + 6144);
    const int j = local & 7, l = (local >> 3) & 63;
    const int rest = local >> 9;                    // 0..7
    const int ks = rest & 1, mt = rest >> 1;
    const int m   = mt * 16 + (l & 15);             // 0..63
    const int kap = ks * 32 + (l >> 4) * 8 + j;     // 0..63
    float v = 0.f;
    if (kap < 48) {
      const int k2 = kap % 24;
      const int m2 = m & 31;
      float s, c;
      sincosf((float)((k2 * m2) % 32) * TWO_PI_32, &s, &c);
      if (m < 32) v = (kap < 24) ? c : -s;   // Zr = sum Wr*c - Wi*s
      else        v = (kap < 24) ? s :  c;   // Zi = sum Wr*s + Wi*c
    }
    const _Float16 h = (_Float16)v;
    MB2frag[0][mt][ks][l][j] = h;
    MB2frag[1][mt][ks][l][j] = (_Float16)(v - (float)h);
  } else if (idx < 15360) {                         // K3: TB3 (B3 B-matrix)
    const int local = idx - (3072 + 6144 + 4096);
    const int j = local & 7, l = (local >> 3) & 63;
    const int rest = local >> 9;                    // 0..3
    const int ks = rest & 1, nt = rest >> 1;
    const int m3  = nt * 16 + (l & 15);             // col 0..31
    const int kap = ks * 32 + (l >> 4) * 8 + j;     // 0..63
    float v = 0.f;
    if (kap < 48) {
      const int k3 = kap % 24;
      float s, c;
      sincosf((float)((k3 * m3) % 32) * TWO_PI_32, &s, &c);
      v = (kap < 24) ? c : -s;               // out = sum Zr*c - Zi*s
    }
    const _Float16 h = (_Float16)v;
    TB3frag[0][nt][ks][l][j] = h;
    TB3frag[1][nt][ks][l][j] = (_Float16)(v - (float)h);
  }
}

__device__ inline void split8(const float* qf, half8& h, half8& lo) {
#pragma unroll
  for (int j = 0; j < 8; ++j) {
    const _Float16 hh = (_Float16)qf[j];
    h[j]  = hh;
    lo[j] = (_Float16)(qf[j] - (float)hh);
  }
}

// ---------------- K1: 4 independent waves/block, 256 thr, grid 12 x 256, ZERO barriers ----------------
// Per-wave LDS: float U[48][68] (13056 B) at pool + wave*13056; D2 overlays after
// GEMM2 (U dead; DS pipe in-order per wave). U stored f32 single-copy; hi/lo split
// at READ time (bit-identical to stored-pair, verified r22).
// launch_bounds(256,3): 3 waves/SIMD target -> VGPR cap ~170; LDS 52224 B -> 3
// blocks/CU = 12 waves/CU. 3072 blocks = 4x fewer dispatches than 1-wave blocks.
__global__ __launch_bounds__(256, 3) void k1_waveslab(const float* __restrict__ x,
                                                      float2* __restrict__ V) {
  const int bx   = blockIdx.x;          // 0..11
  const int bc   = blockIdx.y;          // 0..255
  const int wv   = threadIdx.x >> 6;    // 0..3 (wave-uniform)
  const int lane = threadIdx.x & 63;    // 0..63
  const int n1   = bx * 4 + wv;         // 0..47

  __shared__ __align__(16) float pool[4 * 48 * 68];
  float* U  = pool + wv * (48 * 68);    // wave-private [48][68]
  float* D2 = U;

  const int c16  = lane & 15;
  const int kgrp = lane >> 4;    // 0..3
  const int kb   = kgrp * 8;

  // twiddle fragments (all tiles; this wave does the whole slab)
  half8 t1h[3][2], t1l[3][2], t2h[3][2], t2l[3][2];
#pragma unroll
  for (int mt = 0; mt < 3; ++mt)
#pragma unroll
    for (int ks = 0; ks < 2; ++ks) {
      t1h[mt][ks] = *(const half8*)&T1frag[0][mt][ks][lane][0];
      t1l[mt][ks] = *(const half8*)&T1frag[1][mt][ks][lane][0];
      t2h[mt][ks] = *(const half8*)&T2frag[0][mt][ks][lane][0];
      t2l[mt][ks] = *(const half8*)&T2frag[1][mt][ks][lane][0];
    }

  // zero U pad cols 48..63 (192 float4 over 64 lanes; 16B-aligned). Data dump
  // touches cols 0..47 only -> disjoint; same-wave lgkmcnt orders vs GEMM2 reads.
#pragma unroll
  for (int p = 0; p < 3; ++p) {
    const int fl = lane + 64 * p;           // 0..191
    const int row = fl >> 2, c4 = fl & 3;
    *(f32x4*)&U[row * 68 + 48 + c4 * 4] = (f32x4){};
  }

  const float* xs = x + (size_t)(bc * 48 + n1) * 2304;

  // ---- GEMM1: D1 = T1 * X, per col-tile nt; U dump after each nt ----
  float4 fa0, fb0, fa1, fb1;                  // ks=0 / ks=1 fragment halves
  {
    const float4* p0 = (const float4*)(xs + c16 * 48 + kb);
    fa0 = p0[0]; fb0 = p0[1];
    const int k1i = 32 + kb;
    if (k1i < 48) {
      const float4* p1 = (const float4*)(xs + c16 * 48 + k1i);
      fa1 = p1[0]; fb1 = p1[1];
    } else { fa1 = make_float4(0.f,0.f,0.f,0.f); fb1 = fa1; }
  }

#pragma unroll
  for (int nt = 0; nt < 3; ++nt) {
    float4 na0, nb0, na1, nb1;
    if (nt < 2) {
      const int c = (nt + 1) * 16 + c16;
      const float4* p0 = (const float4*)(xs + c * 48 + kb);
      na0 = p0[0]; nb0 = p0[1];
      const int k1i = 32 + kb;
      if (k1i < 48) {
        const float4* p1 = (const float4*)(xs + c * 48 + k1i);
        na1 = p1[0]; nb1 = p1[1];
      } else { na1 = make_float4(0.f,0.f,0.f,0.f); nb1 = na1; }
    }

    f32x4 acc0 = {}, acc1 = {}, acc2 = {};
#pragma unroll
    for (int ks = 0; ks < 2; ++ks) {
      const float4 qa = ks ? fa1 : fa0;
      const float4 qb = ks ? fb1 : fb0;
      const float qf[8] = {qa.x, qa.y, qa.z, qa.w, qb.x, qb.y, qb.z, qb.w};
      half8 bh, bl;
      split8(qf, bh, bl);
#pragma unroll
      for (int mt = 0; mt < 3; ++mt) {
        f32x4& acc = (mt == 0) ? acc0 : (mt == 1) ? acc1 : acc2;
        acc = __builtin_amdgcn_mfma_f32_16x16x32_f16(t1h[mt][ks], bh, acc, 0, 0, 0);
        acc = __builtin_amdgcn_mfma_f32_16x16x32_f16(t1h[mt][ks], bl, acc, 0, 0, 0);
        acc = __builtin_amdgcn_mfma_f32_16x16x32_f16(t1l[mt][ks], bh, acc, 0, 0, 0);
      }
    }

    // U dump for this nt: f32 single write per element
    {
      const int cc = nt * 16 + c16;
#pragma unroll
      for (int mt = 0; mt < 3; ++mt) {
        const int r0 = mt * 16 + kgrp * 4;
        const f32x4 acc = (mt == 0) ? acc0 : (mt == 1) ? acc1 : acc2;
#pragma unroll
        for (int r = 0; r < 4; ++r)
          U[(r0 + r) * 68 + cc] = acc[r];
      }
    }

    fa0 = na0; fb0 = nb0; fa1 = na1; fb1 = nb1;
  }

  // ---- GEMM2: D2 = U * T2t, all 9 output tiles held in VGPRs ----
  // A-frag: two aligned float4 from U row, split8 at read time; per-acc order
  // identical to r20 (ks0 {h*t2h, h*t2l, l*t2h} then ks1).
  f32x4 a2[3][3] = {};   // [mt][nt2], fully unrolled indices (static)
#pragma unroll
  for (int ks = 0; ks < 2; ++ks) {
#pragma unroll
    for (int mt = 0; mt < 3; ++mt) {
      const float4 q0 = *(const float4*)&U[(mt * 16 + c16) * 68 + ks * 32 + kb];
      const float4 q1 = *(const float4*)&U[(mt * 16 + c16) * 68 + ks * 32 + kb + 4];
      const float qf[8] = {q0.x, q0.y, q0.z, q0.w, q1.x, q1.y, q1.z, q1.w};
      half8 ah, al;
      split8(qf, ah, al);
#pragma unroll
      for (int nt2 = 0; nt2 < 3; ++nt2) {
        a2[mt][nt2] = __builtin_amdgcn_mfma_f32_16x16x32_f16(ah, t2h[nt2][ks], a2[mt][nt2], 0, 0, 0);
        a2[mt][nt2] = __builtin_amdgcn_mfma_f32_16x16x32_f16(ah, t2l[nt2][ks], a2[mt][nt2], 0, 0, 0);
        a2[mt][nt2] = __builtin_amdgcn_mfma_f32_16x16x32_f16(al, t2h[nt2][ks], a2[mt][nt2], 0, 0, 0);
      }
    }
  }

  // D2 dump overlaying U (all U reads issued above; DS pipe in-order per wave)
#pragma unroll
  for (int mt = 0; mt < 3; ++mt)
#pragma unroll
    for (int nt2 = 0; nt2 < 3; ++nt2) {
      const int r0 = mt * 16 + kgrp * 4;
      const int cc = nt2 * 16 + c16;
#pragma unroll
      for (int r = 0; r < 4; ++r)
        D2[(r0 + r) * 68 + cc] = a2[mt][nt2][r];
    }

  // epilogue: recombine -> V[bc][k3][n1][k2] (576 float2; 9 per lane)
#pragma unroll
  for (int q = 0; q < 9; ++q) {
    const int idx = lane + 64 * q;          // 0..575
    const int k3 = idx / 24, k2 = idx % 24;
    const float grr = D2[k3 * 68 + k2];
    const float gis = D2[(k3 + 24) * 68 + k2 + 24];
    const float gir = D2[(k3 + 24) * 68 + k2];
    const float grs = D2[k3 * 68 + k2 + 24];
    V[(size_t)bc * 27648 + (size_t)k3 * 1152 + n1 * 24 + k2] =
        make_float2(grr + gis, gir - grs);
  }
}

// ---------------- K2: A3+B1 fused MFMA GEMM (192 thr, grid 24 x 64, 2 bc-pairs/block) ----------------
// Writes W[bc][m1][k3][k2] (separate buffer, m1-major) so K3 reads are contiguous.
__global__ __launch_bounds__(192) void k2_mfma(const float2* __restrict__ V,
                                               float2* __restrict__ W) {
  const int k3   = blockIdx.x;    // 0..23
  const int byy  = blockIdx.y;    // 0..63 -> bcp = byy*2+g
  const int tid  = threadIdx.x;
  const int lane = tid & 63;
  const int w    = tid >> 6;      // 0..2

  __shared__ __align__(16) float Bb[48 * 100];  // [col=s*24+k2][kap 0..95]

  half8 kth[4][3], ktl[4][3];
#pragma unroll
  for (int mt = 0; mt < 4; ++mt)
#pragma unroll
    for (int ks = 0; ks < 3; ++ks) {
      kth[mt][ks] = *(const half8*)&TK2frag[0][mt][ks][lane][0];
      ktl[mt][ks] = *(const half8*)&TK2frag[1][mt][ks][lane][0];
    }

  const int kbase = (lane >> 4) * 8;
  const int c16   = lane & 15;
  const int cc    = w * 16 + c16;       // 0..47
  const int sE    = cc / 24, k2E = cc % 24;
  const int rbase = (lane >> 4) * 4;

  // prologue prefetch (g=0): 6 float4/thread; s = jj/3, r = tid + 192*(jj%3)
  float4 vr[6];
  {
    const float4* g0 = (const float4*)(V + ((size_t)((byy * 4 + 0) * 24 + k3)) * 1152);
    const float4* g1 = (const float4*)(V + ((size_t)((byy * 4 + 1) * 24 + k3)) * 1152);
#pragma unroll
    for (int jj = 0; jj < 6; ++jj)
      vr[jj] = (jj < 3 ? g0 : g1)[tid + 192 * (jj % 3)];
  }

  for (int g = 0; g < 2; ++g) {
    const int bcp = byy * 2 + g;

    if (g) __syncthreads();   // prev iteration's Bb reads done

    // stage from prefetched regs
#pragma unroll
    for (int jj = 0; jj < 6; ++jj) {
      const int s = jj / 3;
      const int r = tid + 192 * (jj % 3);     // 0..575 within slab
      const int n1 = r / 12, c4 = r % 12;
      const float4 f = vr[jj];
      float* bp = &Bb[(s * 24 + c4 * 2) * 100 + n1];
      bp[0]   = f.x;  bp[48]  = f.y;
      bp[100] = f.z;  bp[148] = f.w;
    }
    // prefetch next bc-pair
    if (g < 1) {
      const float4* g0 = (const float4*)(V + ((size_t)((bcp * 2 + 2) * 24 + k3)) * 1152);
      const float4* g1 = (const float4*)(V + ((size_t)((bcp * 2 + 3) * 24 + k3)) * 1152);
#pragma unroll
      for (int jj = 0; jj < 6; ++jj)
        vr[jj] = (jj < 3 ? g0 : g1)[tid + 192 * (jj % 3)];
    }
    __syncthreads();

    f32x4 a0 = {}, a1 = {}, a2 = {}, a3 = {};
#pragma unroll
    for (int ks = 0; ks < 3; ++ks) {
      const float4 q0 = *(const float4*)&Bb[cc * 100 + ks * 32 + kbase];
      const float4 q1 = *(const float4*)&Bb[cc * 100 + ks * 32 + kbase + 4];
      const float qf[8] = {q0.x, q0.y, q0.z, q0.w, q1.x, q1.y, q1.z, q1.w};
      half8 bh, bl;
      split8(qf, bh, bl);
#pragma unroll
      for (int mt = 0; mt < 4; ++mt) {
        f32x4& acc = (mt == 0) ? a0 : (mt == 1) ? a1 : (mt == 2) ? a2 : a3;
        acc = __builtin_amdgcn_mfma_f32_16x16x32_f16(kth[mt][ks], bh, acc, 0, 0, 0);
        acc = __builtin_amdgcn_mfma_f32_16x16x32_f16(kth[mt][ks], bl, acc, 0, 0, 0);
        acc = __builtin_amdgcn_mfma_f32_16x16x32_f16(ktl[mt][ks], bh, acc, 0, 0, 0);
      }
    }

    // epilogue: rows 0..31 = Wr, rows 32..63 = Wi -> W[bc][m1][k3][k2]
    const int bc = bcp * 2 + sE;
    float2* wp = W + (size_t)bc * 18432 + (size_t)k3 * 24 + k2E;
#pragma unroll
    for (int mt = 0; mt < 2; ++mt) {
      const f32x4 wr = (mt == 0) ? a0 : a1;
      const f32x4 wi = (mt == 0) ? a2 : a3;
#pragma unroll
      for (int r = 0; r < 4; ++r) {
        const int m1 = mt * 16 + rbase + r;
        wp[(size_t)m1 * 576] = make_float2(wr[r], wi[r]);
      }
    }
  }
}

// ---------------- K3: B2 + B3 chained MFMA (128 thr, grid 32 x 128, 2 bc/block) ----------------
// Reads W[bc][m1][k3][k2]: 288 contiguous float4 per (bc,m1).
// Race audit: stage(g) writes Bt; readers GEMM1(g-1) all pre-b2(g-1). relayout(g)
// writes Zb; readers GEMM2(g-1) all pre-b1(g). GEMM2(g) reads Zb written pre-b2(g).
__global__ __launch_bounds__(128) void k3_mfma(const float2* __restrict__ W,
                                               float* __restrict__ out) {
  const int m1   = blockIdx.x;   // 0..31
  const int byy  = blockIdx.y;   // 0..127 -> bc = byy*2+g
  const int tid  = threadIdx.x;
  const int lane = tid & 63;
  const int w    = tid >> 6;     // 0..1

  __shared__ __align__(16) float Bt[32 * 68];   // [col=k3][kap: k2|24+k2|pad]
  __shared__ __align__(16) float Zb[32 * 68];   // [m2][kap: k3|24+k3|pad]

  half8 mbh[4][2], mbl[4][2];
#pragma unroll
  for (int mt = 0; mt < 4; ++mt)
#pragma unroll
    for (int ks = 0; ks < 2; ++ks) {
      mbh[mt][ks] = *(const half8*)&MB2frag[0][mt][ks][lane][0];
      mbl[mt][ks] = *(const half8*)&MB2frag[1][mt][ks][lane][0];
    }
  half8 tb3h[2], tb3l[2];
#pragma unroll
  for (int ks = 0; ks < 2; ++ks) {
    tb3h[ks] = *(const half8*)&TB3frag[0][w][ks][lane][0];
    tb3l[ks] = *(const half8*)&TB3frag[1][w][ks][lane][0];
  }

  // zero pad regions ONCE (data writes never touch them)
  for (int i = tid; i < 8 * 68; i += 128)  Bt[(24 + i / 68) * 68 + (i % 68)] = 0.f;
  for (int i = tid; i < 24 * 20; i += 128) Bt[(i / 20) * 68 + 48 + (i % 20)] = 0.f;
  for (int i = tid; i < 32 * 20; i += 128) Zb[(i / 20) * 68 + 48 + (i % 20)] = 0.f;

  const int kbase = (lane >> 4) * 8;
  const int c16   = lane & 15;
  const int cc    = w * 16 + c16;
  const int rbase = (lane >> 4) * 4;

  // prologue prefetch (g=0): 288 contiguous float4 (jj=2 only tid<32)
  float4 vr0, vr1, vr2;
  {
    const float4* g4 = (const float4*)(W + (size_t)(byy * 2) * 18432 + (size_t)m1 * 576);
    vr0 = g4[tid];
    vr1 = g4[tid + 128];
    if (tid < 32) vr2 = g4[tid + 256];
  }

  for (int g = 0; g < 2; ++g) {
    const int bc = byy * 2 + g;

    // stage Bt from prefetched regs
    {
      const float4 fr[3] = {vr0, vr1, vr2};
#pragma unroll
      for (int jj = 0; jj < 3; ++jj) {
        const int i4 = tid + 128 * jj;
        if (jj < 2 || tid < 32) {
          const int k3 = i4 / 12, c4 = i4 % 12;
          const float4 f = fr[jj];
          Bt[k3 * 68 + 2 * c4]          = f.x;
          Bt[k3 * 68 + 24 + 2 * c4]     = f.y;
          Bt[k3 * 68 + 2 * c4 + 1]      = f.z;
          Bt[k3 * 68 + 24 + 2 * c4 + 1] = f.w;
        }
      }
    }
    // prefetch next bc
    if (g < 1) {
      const float4* g4 = (const float4*)(W + (size_t)(bc + 1) * 18432 + (size_t)m1 * 576);
      vr0 = g4[tid];
      vr1 = g4[tid + 128];
      if (tid < 32) vr2 = g4[tid + 256];
    }
    __syncthreads();   // b1: Bt staged (and prev GEMM2's Zb reads done)

    // GEMM1: [Zr;Zi](64 x k3) = MB2 * [Wr;Wi]
    f32x4 z0 = {}, z1 = {}, z2 = {}, z3 = {};
#pragma unroll
    for (int ks = 0; ks < 2; ++ks) {
      const float4 q0 = *(const float4*)&Bt[cc * 68 + ks * 32 + kbase];
      const float4 q1 = *(const float4*)&Bt[cc * 68 + ks * 32 + kbase + 4];
      const float qf[8] = {q0.x, q0.y, q0.z, q0.w, q1.x, q1.y, q1.z, q1.w};
      half8 bh, bl;
      split8(qf, bh, bl);
#pragma unroll
      for (int mt = 0; mt < 4; ++mt) {
        f32x4& acc = (mt == 0) ? z0 : (mt == 1) ? z1 : (mt == 2) ? z2 : z3;
        acc = __builtin_amdgcn_mfma_f32_16x16x32_f16(mbh[mt][ks], bh, acc, 0, 0, 0);
        acc = __builtin_amdgcn_mfma_f32_16x16x32_f16(mbh[mt][ks], bl, acc, 0, 0, 0);
        acc = __builtin_amdgcn_mfma_f32_16x16x32_f16(mbl[mt][ks], bh, acc, 0, 0, 0);
      }
    }
    // relayout: Zb[m2][k3] = Zr, Zb[m2][24+k3] = Zi
    if (cc < 24) {
#pragma unroll
      for (int mt = 0; mt < 4; ++mt) {
        const f32x4 acc = (mt == 0) ? z0 : (mt == 1) ? z1 : (mt == 2) ? z2 : z3;
        const int row0 = mt * 16 + rbase;
#pragma unroll
        for (int r = 0; r < 4; ++r) {
          const int row = row0 + r;
          if (row < 32) Zb[row * 68 + cc]              = acc[r];
          else          Zb[(row - 32) * 68 + 24 + cc]  = acc[r];
        }
      }
    }
    __syncthreads();   // b2: Zb visible (and all Bt reads done)

    // GEMM2: out(32x32) = Z(32 x 48p64) * TB3
    f32x4 o0 = {}, o1 = {};
#pragma unroll
    for (int ks = 0; ks < 2; ++ks) {
#pragma unroll
      for (int mt = 0; mt < 2; ++mt) {
        const float4 q0 = *(const float4*)&Zb[(mt * 16 + c16) * 68 + ks * 32 + kbase];
        const float4 q1 = *(const float4*)&Zb[(mt * 16 + c16) * 68 + ks * 32 + kbase + 4];
        const float qf[8] = {q0.x, q0.y, q0.z, q0.w, q1.x, q1.y, q1.z, q1.w};
        half8 ah, al;
        split8(qf, ah, al);
        f32x4& acc = (mt == 0) ? o0 : o1;
        acc = __builtin_amdgcn_mfma_f32_16x16x32_f16(ah, tb3h[ks], acc, 0, 0, 0);
        acc = __builtin_amdgcn_mfma_f32_16x16x32_f16(ah, tb3l[ks], acc, 0, 0, 0);
        acc = __builtin_amdgcn_mfma_f32_16x16x32_f16(al, tb3h[ks], acc, 0, 0, 0);
      }
    }
    float* op = out + (size_t)(bc * 32 + m1) * 1024;
#pragma unroll
    for (int mt = 0; mt < 2; ++mt) {
      const f32x4 acc = (mt == 0) ? o0 : o1;
#pragma unroll
      for (int r = 0; r < 4; ++r) {
        const int m2 = mt * 16 + rbase + r;
        op[m2 * 32 + cc] = acc[r] * NORM_F;
      }
    }
  }

  // set lazy-init flag: runs strictly after k_init_tw in stream order, so the
  // NEXT kernel_launch's k_init_tw can safely early-exit (tables are pure consts).
  if (tid == 0 && blockIdx.x == 0 && blockIdx.y == 0) g_twdone = 1;
}

extern "C" void kernel_launch(void* const* d_in, const int* in_sizes, int n_in,
                              void* d_out, int out_size, void* d_ws, size_t ws_size,
                              hipStream_t stream) {
  const float* x = (const float*)d_in[0];
  float* out = (float*)d_out;
  float2* V = (float2*)d_ws;                                   // 56,623,104 B
  float2* W = (float2*)((char*)d_ws + 56623104);               // 37,748,736 B

  k_init_tw   <<<dim3(60), dim3(256), 0, stream>>>();
  k1_waveslab <<<dim3(12, 256), dim3(256), 0, stream>>>(x, V);
  k2_mfma     <<<dim3(24, 64), dim3(192), 0, stream>>>(V, W);
  k3_mfma     <<<dim3(32, 128), dim3(128), 0, stream>>>(W, out);
}